// Round 1
// baseline (1287.811 us; speedup 1.0000x reference)
//
#include <hip/hip_runtime.h>

typedef __bf16 bf16;
typedef __bf16 bf16x8 __attribute__((ext_vector_type(8)));
typedef __bf16 bf16x4 __attribute__((ext_vector_type(4)));
typedef float f32x4 __attribute__((ext_vector_type(4)));

#define MFMA16(a, b, c) __builtin_amdgcn_mfma_f32_16x16x32_bf16(a, b, c, 0, 0, 0)

// ---------------------------------------------------------------------------
// Weight transpose+convert: Wt[n*K + k] = (bf16) W[k*N + n]
__global__ __launch_bounds__(256) void wconv_k(const float* __restrict__ W,
                                               bf16* __restrict__ Wt,
                                               int K, int N) {
  long long idx = (long long)blockIdx.x * 256 + threadIdx.x;
  if (idx >= (long long)K * N) return;
  int k = (int)(idx % K);
  int n = (int)(idx / K);
  Wt[idx] = (bf16)W[(long long)k * N + n];
}

// ---------------------------------------------------------------------------
// V transpose to padded per-frame layout:
// Vt[((bh*8+fr)*64 + d)*224 + k] = Vb[(bh*1568 + fr*196 + k)*64 + d], zero pad k>=196
__global__ __launch_bounds__(256) void transv_k(const bf16* __restrict__ Vb,
                                                bf16* __restrict__ Vt) {
  long long idx = (long long)blockIdx.x * 256 + threadIdx.x;
  const long long total = (long long)384 * 8 * 64 * 224;
  if (idx >= total) return;
  int k = (int)(idx % 224);
  long long t = idx / 224;
  int d = (int)(t % 64);
  t /= 64;
  int fr = (int)(t % 8);
  int bh = (int)(t / 8);
  bf16 v = (bf16)0.0f;
  if (k < 196) v = Vb[((long long)bh * 1568 + fr * 196 + k) * 64 + d];
  Vt[idx] = v;
}

// ---------------------------------------------------------------------------
// Tiled bf16 MFMA GEMM: C(MxN) = A(MxK) * Bt(NxK)^T
// MODE 0: A=f32 (question), C = bf16 q, scaled by 0.125
// MODE 1: A=f32 (x), C -> Kb (cols 0..767), C2 -> Vb (cols 768..1535), heads layout
// MODE 2: A=bf16 (O), C = f32 out + bias
template <int MODE>
__global__ __launch_bounds__(256) void gemm_k(const void* __restrict__ Aptr,
                                              const bf16* __restrict__ Bt,
                                              void* __restrict__ Cptr,
                                              bf16* __restrict__ C2,
                                              const float* __restrict__ bias,
                                              int M, int N, int K) {
  __shared__ bf16 As[128 * 72];  // pitch 72 elems (144 B) keeps 16B align + breaks banks
  __shared__ bf16 Bs[128 * 72];
  const int tid = threadIdx.x;
  const int lane = tid & 63, w = tid >> 6;
  const int wm = w & 1, wn = w >> 1;
  const int col = lane & 15, quad = lane >> 4;
  const int m0 = blockIdx.x * 128, n0 = blockIdx.y * 128;
  f32x4 acc[4][4] = {};

  for (int k0 = 0; k0 < K; k0 += 64) {
    __syncthreads();
    if (MODE == 2) {
      const bf16* A = (const bf16*)Aptr;
#pragma unroll
      for (int it = 0; it < 4; ++it) {
        int slot = tid + it * 256;       // 1024 slots: 128 rows x 8 segs of 8 elems
        int r = slot >> 3, s = slot & 7;
        int gm = m0 + r;
        bf16x8 v;
        if (gm < M) {
          v = *(const bf16x8*)(A + (long long)gm * K + k0 + s * 8);
        } else {
#pragma unroll
          for (int i = 0; i < 8; ++i) v[i] = (bf16)0.0f;
        }
        *(bf16x8*)&As[r * 72 + s * 8] = v;
      }
    } else {
      const float* A = (const float*)Aptr;
#pragma unroll
      for (int it = 0; it < 8; ++it) {
        int slot = tid + it * 256;       // 2048 slots: 128 rows x 16 segs of 4 elems
        int r = slot >> 4, s = slot & 15;
        int gm = m0 + r;
        float x0 = 0.f, x1 = 0.f, x2 = 0.f, x3 = 0.f;
        if (gm < M) {
          const float4 vv = *(const float4*)(A + (long long)gm * K + k0 + s * 4);
          x0 = vv.x; x1 = vv.y; x2 = vv.z; x3 = vv.w;
        }
        bf16x4 v;
        v[0] = (bf16)x0; v[1] = (bf16)x1; v[2] = (bf16)x2; v[3] = (bf16)x3;
        *(bf16x4*)&As[r * 72 + s * 4] = v;
      }
    }
    // B tile (always bf16, pre-transposed weights, N rows of K)
#pragma unroll
    for (int it = 0; it < 4; ++it) {
      int slot = tid + it * 256;
      int r = slot >> 3, s = slot & 7;
      *(bf16x8*)&Bs[r * 72 + s * 8] =
          *(const bf16x8*)(Bt + (long long)(n0 + r) * K + k0 + s * 8);
    }
    __syncthreads();
#pragma unroll
    for (int kk = 0; kk < 64; kk += 32) {
      bf16x8 af[4], bfr[4];
#pragma unroll
      for (int mt = 0; mt < 4; ++mt)
        af[mt] = *(const bf16x8*)&As[(wm * 64 + mt * 16 + col) * 72 + kk + quad * 8];
#pragma unroll
      for (int nt = 0; nt < 4; ++nt)
        bfr[nt] = *(const bf16x8*)&Bs[(wn * 64 + nt * 16 + col) * 72 + kk + quad * 8];
#pragma unroll
      for (int mt = 0; mt < 4; ++mt) {
#pragma unroll
        for (int nt = 0; nt < 4; ++nt)
          acc[mt][nt] = MFMA16(af[mt], bfr[nt], acc[mt][nt]);
      }
    }
  }

  // Epilogue. C/D layout: col = lane&15, row = quad*4 + reg  [m89-verified]
#pragma unroll
  for (int mt = 0; mt < 4; ++mt) {
#pragma unroll
    for (int nt = 0; nt < 4; ++nt) {
      const int gn = n0 + wn * 64 + nt * 16 + col;
      float bv = 0.f;
      if (MODE == 2) bv = bias[gn];
#pragma unroll
      for (int r = 0; r < 4; ++r) {
        const int gm = m0 + wm * 64 + mt * 16 + quad * 4 + r;
        if (gm >= M) continue;
        const float v = acc[mt][nt][r];
        if (MODE == 0) {
          ((bf16*)Cptr)[(long long)gm * N + gn] = (bf16)(v * 0.125f);
        } else if (MODE == 1) {
          const int b = gm / 1568, j = gm - b * 1568;
          if (gn < 768) {
            const int hh = gn >> 6, dd = gn & 63;
            ((bf16*)Cptr)[((long long)(b * 12 + hh) * 1568 + j) * 64 + dd] = (bf16)v;
          } else {
            const int g2 = gn - 768;
            const int hh = g2 >> 6, dd = g2 & 63;
            C2[((long long)(b * 12 + hh) * 1568 + j) * 64 + dd] = (bf16)v;
          }
        } else {
          ((float*)Cptr)[(long long)gm * N + gn] = v + bv;
        }
      }
    }
  }
}

// ---------------------------------------------------------------------------
// Framed attention: one block per (bh, fr). 4 waves, each owns M-tiles of 16
// queries (13 tiles cover 196 queries padded to 208). K/Q/V fragments read
// directly from global (per-frame K/V slice is 28 KB -> L1 resident); only the
// P C-layout -> A-layout transpose goes through LDS (per-wave buffer).
__global__ __launch_bounds__(256) void attn_k(const bf16* __restrict__ qs,
                                              const bf16* __restrict__ Kb,
                                              const bf16* __restrict__ Vt,
                                              bf16* __restrict__ Ob) {
  __shared__ bf16 Pt[4][16 * 264];  // pitch 264 elems: 16B aligned, bank-spread
  const int bh = blockIdx.x, fr = blockIdx.y;
  const int b = bh / 12, h = bh % 12;
  const int tid = threadIdx.x, lane = tid & 63, w = tid >> 6;
  const int col = lane & 15, quad = lane >> 4;
  const bf16* Qb = qs + (long long)b * 197 * 768 + h * 64;
  const bf16* Kbase = Kb + ((long long)bh * 1568 + fr * 196) * 64;
  const bf16* Vbase = Vt + (long long)(bh * 8 + fr) * 64 * 224;
  bf16* Pw = &Pt[w][0];

  for (int mt = w; mt < 13; mt += 4) {
    const int qq = mt * 16 + col;              // query index for A-frag (lane&15)
    const int tok = (qq < 196) ? (qq + 1) : 196;  // clamp padded rows (discarded)
    const bf16* qp = Qb + (long long)tok * 768;
    const bf16x8 aq0 = *(const bf16x8*)(qp + quad * 8);
    const bf16x8 aq1 = *(const bf16x8*)(qp + 32 + quad * 8);

    f32x4 sim[14];
#pragma unroll
    for (int nt = 0; nt < 14; ++nt) {
      const int key = nt * 16 + col;           // key index for B-frag (lane&15)
      const int kr = (key < 196) ? key : 195;  // clamp (masked below)
      const bf16* kp = Kbase + (long long)kr * 64 + quad * 8;
      const bf16x8 bk0 = *(const bf16x8*)kp;
      const bf16x8 bk1 = *(const bf16x8*)(kp + 32);
      f32x4 s = {0.f, 0.f, 0.f, 0.f};
      s = MFMA16(aq0, bk0, s);
      s = MFMA16(aq1, bk1, s);
      if (key >= 196) { s[0] = -1e30f; s[1] = -1e30f; s[2] = -1e30f; s[3] = -1e30f; }
      sim[nt] = s;
    }

    // Row softmax. Row m = quad*4 + r lives in the 16 lanes sharing `quad`.
    float inv[4];
#pragma unroll
    for (int r = 0; r < 4; ++r) {
      float mx = -1e30f;
#pragma unroll
      for (int nt = 0; nt < 14; ++nt) mx = fmaxf(mx, sim[nt][r]);
#pragma unroll
      for (int msk = 1; msk < 16; msk <<= 1) mx = fmaxf(mx, __shfl_xor(mx, msk, 64));
      float sum = 0.f;
#pragma unroll
      for (int nt = 0; nt < 14; ++nt) {
        const float p = __expf(sim[nt][r] - mx);
        sim[nt][r] = p;
        sum += p;
      }
#pragma unroll
      for (int msk = 1; msk < 16; msk <<= 1) sum += __shfl_xor(sum, msk, 64);
      inv[r] = 1.f / sum;
    }

    // Drain previous iteration's P reads before overwriting the wave buffer.
    __asm__ volatile("s_waitcnt lgkmcnt(0)" ::: "memory");
#pragma unroll
    for (int nt = 0; nt < 14; ++nt) {
#pragma unroll
      for (int r = 0; r < 4; ++r) {
        Pw[(quad * 4 + r) * 264 + nt * 16 + col] = (bf16)(sim[nt][r] * inv[r]);
      }
    }
    __asm__ volatile("s_waitcnt lgkmcnt(0)" ::: "memory");

    bf16x8 pa[7];
#pragma unroll
    for (int ks = 0; ks < 7; ++ks)
      pa[ks] = *(const bf16x8*)&Pw[col * 264 + ks * 32 + quad * 8];

#pragma unroll
    for (int dt = 0; dt < 4; ++dt) {
      f32x4 o = {0.f, 0.f, 0.f, 0.f};
#pragma unroll
      for (int ks = 0; ks < 7; ++ks) {
        const bf16x8 bv =
            *(const bf16x8*)(Vbase + (long long)(dt * 16 + col) * 224 + ks * 32 + quad * 8);
        o = MFMA16(pa[ks], bv, o);
      }
#pragma unroll
      for (int r = 0; r < 4; ++r) {
        const int q2 = mt * 16 + quad * 4 + r;
        if (q2 < 196) {
          const int token = 1 + fr * 196 + q2;
          Ob[((long long)b * 1569 + token) * 768 + h * 64 + dt * 16 + col] = (bf16)o[r];
        }
      }
    }
  }
}

// ---------------------------------------------------------------------------
// cls-token attention: one block per (b,h); 1 query over all 1568 keys.
__global__ __launch_bounds__(256) void cls_k(const bf16* __restrict__ qs,
                                             const bf16* __restrict__ Kb,
                                             const bf16* __restrict__ Vt,
                                             bf16* __restrict__ Ob) {
  __shared__ float qsm[64];
  __shared__ float ssm[1568];
  __shared__ float red[256];
  __shared__ float osm[4][64];
  const int bh = blockIdx.x;
  const int b = bh / 12, h = bh % 12;
  const int tid = threadIdx.x;
  if (tid < 64) qsm[tid] = (float)qs[(long long)b * 197 * 768 + h * 64 + tid];
  __syncthreads();

  float lmax = -1e30f;
  for (int j = tid; j < 1568; j += 256) {
    const bf16* kp = Kb + ((long long)bh * 1568 + j) * 64;
    float s = 0.f;
#pragma unroll
    for (int seg = 0; seg < 8; ++seg) {
      const bf16x8 kv = *(const bf16x8*)(kp + seg * 8);
#pragma unroll
      for (int i = 0; i < 8; ++i) s += qsm[seg * 8 + i] * (float)kv[i];
    }
    ssm[j] = s;
    lmax = fmaxf(lmax, s);
  }
  red[tid] = lmax;
  __syncthreads();
  for (int sft = 128; sft > 0; sft >>= 1) {
    if (tid < sft) red[tid] = fmaxf(red[tid], red[tid + sft]);
    __syncthreads();
  }
  const float mx = red[0];
  __syncthreads();

  float lsum = 0.f;
  for (int j = tid; j < 1568; j += 256) {
    const float p = __expf(ssm[j] - mx);
    ssm[j] = p;
    lsum += p;
  }
  red[tid] = lsum;
  __syncthreads();
  for (int sft = 128; sft > 0; sft >>= 1) {
    if (tid < sft) red[tid] += red[tid + sft];
    __syncthreads();
  }
  const float inv = 1.f / red[0];
  __syncthreads();

  const int d = tid & 63, c = tid >> 6;
  float acc = 0.f;
  for (int fr = c * 2; fr < c * 2 + 2; ++fr) {
    const bf16* vp = Vt + ((long long)(bh * 8 + fr) * 64 + d) * 224;
    const float* pp = &ssm[fr * 196];
    for (int k = 0; k < 196; ++k) acc += pp[k] * (float)vp[k];
  }
  osm[c][d] = acc;
  __syncthreads();
  if (tid < 64) {
    const float o = (osm[0][tid] + osm[1][tid] + osm[2][tid] + osm[3][tid]) * inv;
    Ob[(long long)b * 1569 * 768 + h * 64 + tid] = (bf16)o;
  }
}

// ---------------------------------------------------------------------------
extern "C" void kernel_launch(void* const* d_in, const int* in_sizes, int n_in,
                              void* d_out, int out_size, void* d_ws, size_t ws_size,
                              hipStream_t stream) {
  const float* x        = (const float*)d_in[0];
  const float* question = (const float*)d_in[1];
  const float* Wq       = (const float*)d_in[2];
  const float* Wkv      = (const float*)d_in[3];
  const float* Wproj    = (const float*)d_in[4];
  const float* bproj    = (const float*)d_in[5];
  float* out = (float*)d_out;

  char* wsb = (char*)d_ws;
  const long long SZ_WQT  = 768LL * 768 * 2;
  const long long SZ_WKVT = 1536LL * 768 * 2;
  const long long SZ_WPT  = 768LL * 768 * 2;
  const long long SZ_Q    = 32LL * 197 * 768 * 2;
  const long long SZ_K    = 384LL * 1568 * 64 * 2;
  const long long SZ_VO   = 50208LL * 768 * 2;  // max(Vb, Ob): Ob aliases dead Vb

  bf16* Wqt  = (bf16*)(wsb);
  bf16* Wkvt = (bf16*)(wsb + SZ_WQT);
  bf16* Wpt  = (bf16*)(wsb + SZ_WQT + SZ_WKVT);
  bf16* qsb  = (bf16*)(wsb + SZ_WQT + SZ_WKVT + SZ_WPT);
  bf16* Kb   = (bf16*)(wsb + SZ_WQT + SZ_WKVT + SZ_WPT + SZ_Q);
  bf16* Vb   = (bf16*)(wsb + SZ_WQT + SZ_WKVT + SZ_WPT + SZ_Q + SZ_K);
  bf16* Ob   = Vb;  // alias: Vb dead after transv_k
  bf16* Vt   = (bf16*)(wsb + SZ_WQT + SZ_WKVT + SZ_WPT + SZ_Q + SZ_K + SZ_VO);

  wconv_k<<<(768 * 768) / 256, 256, 0, stream>>>(Wq, Wqt, 768, 768);
  wconv_k<<<(768 * 1536) / 256, 256, 0, stream>>>(Wkv, Wkvt, 768, 1536);
  wconv_k<<<(768 * 768) / 256, 256, 0, stream>>>(Wproj, Wpt, 768, 768);

  // q = (question @ Wq) * 0.125, bf16
  gemm_k<0><<<dim3(50, 6), 256, 0, stream>>>(question, Wqt, qsb, nullptr, nullptr,
                                             6304, 768, 768);
  // kv = x @ Wkv -> Kb, Vb (heads layout)
  gemm_k<1><<<dim3(392, 12), 256, 0, stream>>>(x, Wkvt, Kb, Vb, nullptr,
                                               50176, 1536, 768);
  // V -> padded transposed layout (consumes Vb; Ob may then reuse its space)
  transv_k<<<(384 * 8 * 64 * 224) / 256, 256, 0, stream>>>(Vb, Vt);

  cls_k<<<384, 256, 0, stream>>>(qsb, Kb, Vt, Ob);
  attn_k<<<dim3(384, 8), 256, 0, stream>>>(qsb, Kb, Vt, Ob);

  // out = O @ Wproj + bproj (f32)
  gemm_k<2><<<dim3(393, 6), 256, 0, stream>>>(Ob, Wpt, out, nullptr, bproj,
                                              50208, 768, 768);
}

// Round 2
// 1062.515 us; speedup vs baseline: 1.2120x; 1.2120x over previous
//
#include <hip/hip_runtime.h>

typedef __bf16 bf16;
typedef __bf16 bf16x8 __attribute__((ext_vector_type(8)));
typedef __bf16 bf16x4 __attribute__((ext_vector_type(4)));
typedef float f32x4 __attribute__((ext_vector_type(4)));

#define MFMA16(a, b, c) __builtin_amdgcn_mfma_f32_16x16x32_bf16(a, b, c, 0, 0, 0)

__device__ __forceinline__ void gload_lds16(const bf16* g, bf16* l) {
  __builtin_amdgcn_global_load_lds(
      (const __attribute__((address_space(1))) void*)g,
      (__attribute__((address_space(3))) void*)l, 16, 0, 0);
}

// ---------------------------------------------------------------------------
// f32 -> bf16 bulk convert, 8 elems/thread (32B load, 16B store)
__global__ __launch_bounds__(256) void f2b_k(const float* __restrict__ src,
                                             bf16* __restrict__ dst,
                                             long long n) {
  long long i = ((long long)blockIdx.x * 256 + threadIdx.x) * 8;
  if (i >= n) return;
  const float4 a = *(const float4*)(src + i);
  const float4 b = *(const float4*)(src + i + 4);
  bf16x8 v;
  v[0] = (bf16)a.x; v[1] = (bf16)a.y; v[2] = (bf16)a.z; v[3] = (bf16)a.w;
  v[4] = (bf16)b.x; v[5] = (bf16)b.y; v[6] = (bf16)b.z; v[7] = (bf16)b.w;
  *(bf16x8*)(dst + i) = v;
}

// ---------------------------------------------------------------------------
// Weight transpose+convert: Wt[n*K + k] = (bf16) W[k*N + n]
__global__ __launch_bounds__(256) void wconv_k(const float* __restrict__ W,
                                               bf16* __restrict__ Wt,
                                               int K, int N) {
  long long idx = (long long)blockIdx.x * 256 + threadIdx.x;
  if (idx >= (long long)K * N) return;
  int k = (int)(idx % K);
  int n = (int)(idx / K);
  Wt[idx] = (bf16)W[(long long)k * N + n];
}

// ---------------------------------------------------------------------------
// V transpose to padded per-frame layout:
// Vt[((bh*8+fr)*64 + d)*224 + k] = Vb[(bh*1568 + fr*196 + k)*64 + d], zero pad
__global__ __launch_bounds__(256) void transv_k(const bf16* __restrict__ Vb,
                                                bf16* __restrict__ Vt) {
  long long idx = (long long)blockIdx.x * 256 + threadIdx.x;
  const long long total = (long long)384 * 8 * 64 * 224;
  if (idx >= total) return;
  int k = (int)(idx % 224);
  long long t = idx / 224;
  int d = (int)(t % 64);
  t /= 64;
  int fr = (int)(t % 8);
  int bh = (int)(t / 8);
  bf16 v = (bf16)0.0f;
  if (k < 196) v = Vb[((long long)bh * 1568 + fr * 196 + k) * 64 + d];
  Vt[idx] = v;
}

// ---------------------------------------------------------------------------
// m97-style bf16 MFMA GEMM: C(MxN) = A(MxK) * Bt(NxK)^T. A is bf16.
// 128x128 tile, BK=64, global_load_lds width-16 staging, XOR-swizzled LDS.
// MODE 0: C = bf16 q, scaled by 0.125
// MODE 1: C -> Kb (cols<768), C2 -> Vb (cols>=768), heads layout
// MODE 2: C = f32 out + bias
template <int MODE>
__global__ __launch_bounds__(256) void gemm_k(const bf16* __restrict__ A,
                                              const bf16* __restrict__ Bt,
                                              void* __restrict__ Cptr,
                                              bf16* __restrict__ C2,
                                              const float* __restrict__ bias,
                                              int M, int N, int K) {
  __shared__ bf16 As[128 * 64];  // pitch 64 elems (contiguous: required by DMA)
  __shared__ bf16 Bs[128 * 64];
  const int tid = threadIdx.x;
  const int lane = tid & 63, w = tid >> 6;
  const int wm = w & 1, wn = w >> 1;
  const int col = lane & 15, quad = lane >> 4;
  const int m0 = blockIdx.x * 128, n0 = blockIdx.y * 128;

  // Staging geometry: instr j of wave w covers tile rows w*32 + j*8 + (lane>>3),
  // 16B chunk (8 bf16). XOR swizzle: LDS slot (lane&7) holds global segment
  // (lane&7)^(lane>>3)  [row&7 == lane>>3 always].
  const int rsub = lane >> 3;
  const int segg = (lane & 7) ^ rsub;
  const bf16* Ag0 = A + (long long)(m0 + w * 32 + rsub) * K + segg * 8;
  const bf16* Bg0 = Bt + (long long)(n0 + w * 32 + rsub) * K + segg * 8;
  bf16* Al0 = As + (w * 32) * 64;  // wave-uniform LDS base (HW adds lane*16B)
  bf16* Bl0 = Bs + (w * 32) * 64;

  f32x4 acc[4][4] = {};
  const int sA = col & 7;  // swizzle term for this lane's A/B fragment rows

  for (int k0 = 0; k0 < K; k0 += 64) {
    __syncthreads();
#pragma unroll
    for (int j = 0; j < 4; ++j)
      gload_lds16(Ag0 + (long long)j * 8 * K + k0, Al0 + j * 8 * 64);
#pragma unroll
    for (int j = 0; j < 4; ++j)
      gload_lds16(Bg0 + (long long)j * 8 * K + k0, Bl0 + j * 8 * 64);
    __syncthreads();

#pragma unroll
    for (int kk2 = 0; kk2 < 2; ++kk2) {
      const int s = kk2 * 4 + quad;     // global k-segment this frag needs
      const int slot = (s ^ sA) * 8;    // swizzled LDS chunk
      bf16x8 af[4], bfr[4];
#pragma unroll
      for (int mt = 0; mt < 4; ++mt)
        af[mt] = *(const bf16x8*)&As[(wm * 64 + mt * 16 + col) * 64 + slot];
#pragma unroll
      for (int nt = 0; nt < 4; ++nt)
        bfr[nt] = *(const bf16x8*)&Bs[(wn * 64 + nt * 16 + col) * 64 + slot];
#pragma unroll
      for (int mt = 0; mt < 4; ++mt) {
#pragma unroll
        for (int nt = 0; nt < 4; ++nt)
          acc[mt][nt] = MFMA16(af[mt], bfr[nt], acc[mt][nt]);
      }
    }
  }

  // Epilogue. C/D layout: col = lane&15, row = quad*4 + reg  [m89-verified]
#pragma unroll
  for (int mt = 0; mt < 4; ++mt) {
#pragma unroll
    for (int nt = 0; nt < 4; ++nt) {
      const int gn = n0 + wn * 64 + nt * 16 + col;
      float bv = 0.f;
      if (MODE == 2) bv = bias[gn];
#pragma unroll
      for (int r = 0; r < 4; ++r) {
        const int gm = m0 + wm * 64 + mt * 16 + quad * 4 + r;
        if (gm >= M) continue;
        const float v = acc[mt][nt][r];
        if (MODE == 0) {
          ((bf16*)Cptr)[(long long)gm * N + gn] = (bf16)(v * 0.125f);
        } else if (MODE == 1) {
          const int b = gm / 1568, j = gm - b * 1568;
          if (gn < 768) {
            const int hh = gn >> 6, dd = gn & 63;
            ((bf16*)Cptr)[((long long)(b * 12 + hh) * 1568 + j) * 64 + dd] = (bf16)v;
          } else {
            const int g2 = gn - 768;
            const int hh = g2 >> 6, dd = g2 & 63;
            C2[((long long)(b * 12 + hh) * 1568 + j) * 64 + dd] = (bf16)v;
          }
        } else {
          ((float*)Cptr)[(long long)gm * N + gn] = v + bv;
        }
      }
    }
  }
}

// ---------------------------------------------------------------------------
// Framed attention: one block per (bh, fr). K/Q/V fragments read directly from
// global (per-frame K/V slice is 28 KB -> L1 resident); only the P
// C-layout -> A-layout transpose goes through LDS (per-wave buffer).
__global__ __launch_bounds__(256) void attn_k(const bf16* __restrict__ qs,
                                              const bf16* __restrict__ Kb,
                                              const bf16* __restrict__ Vt,
                                              bf16* __restrict__ Ob) {
  __shared__ bf16 Pt[4][16 * 264];
  const int bh = blockIdx.x, fr = blockIdx.y;
  const int b = bh / 12, h = bh % 12;
  const int tid = threadIdx.x, lane = tid & 63, w = tid >> 6;
  const int col = lane & 15, quad = lane >> 4;
  const bf16* Qb = qs + (long long)b * 197 * 768 + h * 64;
  const bf16* Kbase = Kb + ((long long)bh * 1568 + fr * 196) * 64;
  const bf16* Vbase = Vt + (long long)(bh * 8 + fr) * 64 * 224;
  bf16* Pw = &Pt[w][0];

  for (int mt = w; mt < 13; mt += 4) {
    const int qq = mt * 16 + col;
    const int tok = (qq < 196) ? (qq + 1) : 196;
    const bf16* qp = Qb + (long long)tok * 768;
    const bf16x8 aq0 = *(const bf16x8*)(qp + quad * 8);
    const bf16x8 aq1 = *(const bf16x8*)(qp + 32 + quad * 8);

    f32x4 sim[14];
#pragma unroll
    for (int nt = 0; nt < 14; ++nt) {
      const int key = nt * 16 + col;
      const int kr = (key < 196) ? key : 195;
      const bf16* kp = Kbase + (long long)kr * 64 + quad * 8;
      const bf16x8 bk0 = *(const bf16x8*)kp;
      const bf16x8 bk1 = *(const bf16x8*)(kp + 32);
      f32x4 s = {0.f, 0.f, 0.f, 0.f};
      s = MFMA16(aq0, bk0, s);
      s = MFMA16(aq1, bk1, s);
      if (key >= 196) { s[0] = -1e30f; s[1] = -1e30f; s[2] = -1e30f; s[3] = -1e30f; }
      sim[nt] = s;
    }

    float inv[4];
#pragma unroll
    for (int r = 0; r < 4; ++r) {
      float mx = -1e30f;
#pragma unroll
      for (int nt = 0; nt < 14; ++nt) mx = fmaxf(mx, sim[nt][r]);
#pragma unroll
      for (int msk = 1; msk < 16; msk <<= 1) mx = fmaxf(mx, __shfl_xor(mx, msk, 64));
      float sum = 0.f;
#pragma unroll
      for (int nt = 0; nt < 14; ++nt) {
        const float p = __expf(sim[nt][r] - mx);
        sim[nt][r] = p;
        sum += p;
      }
#pragma unroll
      for (int msk = 1; msk < 16; msk <<= 1) sum += __shfl_xor(sum, msk, 64);
      inv[r] = 1.f / sum;
    }

    __asm__ volatile("s_waitcnt lgkmcnt(0)" ::: "memory");
#pragma unroll
    for (int nt = 0; nt < 14; ++nt) {
#pragma unroll
      for (int r = 0; r < 4; ++r) {
        Pw[(quad * 4 + r) * 264 + nt * 16 + col] = (bf16)(sim[nt][r] * inv[r]);
      }
    }
    __asm__ volatile("s_waitcnt lgkmcnt(0)" ::: "memory");

    bf16x8 pa[7];
#pragma unroll
    for (int ks = 0; ks < 7; ++ks)
      pa[ks] = *(const bf16x8*)&Pw[col * 264 + ks * 32 + quad * 8];

#pragma unroll
    for (int dt = 0; dt < 4; ++dt) {
      f32x4 o = {0.f, 0.f, 0.f, 0.f};
#pragma unroll
      for (int ks = 0; ks < 7; ++ks) {
        const bf16x8 bv =
            *(const bf16x8*)(Vbase + (long long)(dt * 16 + col) * 224 + ks * 32 + quad * 8);
        o = MFMA16(pa[ks], bv, o);
      }
#pragma unroll
      for (int r = 0; r < 4; ++r) {
        const int q2 = mt * 16 + quad * 4 + r;
        if (q2 < 196) {
          const int token = 1 + fr * 196 + q2;
          Ob[((long long)b * 1569 + token) * 768 + h * 64 + dt * 16 + col] = (bf16)o[r];
        }
      }
    }
  }
}

// ---------------------------------------------------------------------------
// cls-token attention: one block per (b,h); 1 query over all 1568 keys.
__global__ __launch_bounds__(256) void cls_k(const bf16* __restrict__ qs,
                                             const bf16* __restrict__ Kb,
                                             const bf16* __restrict__ Vt,
                                             bf16* __restrict__ Ob) {
  __shared__ float qsm[64];
  __shared__ float ssm[1568];
  __shared__ float red[256];
  __shared__ float osm[4][64];
  const int bh = blockIdx.x;
  const int b = bh / 12, h = bh % 12;
  const int tid = threadIdx.x;
  if (tid < 64) qsm[tid] = (float)qs[(long long)b * 197 * 768 + h * 64 + tid];
  __syncthreads();

  float lmax = -1e30f;
  for (int j = tid; j < 1568; j += 256) {
    const bf16* kp = Kb + ((long long)bh * 1568 + j) * 64;
    float s = 0.f;
#pragma unroll
    for (int seg = 0; seg < 8; ++seg) {
      const bf16x8 kv = *(const bf16x8*)(kp + seg * 8);
#pragma unroll
      for (int i = 0; i < 8; ++i) s += qsm[seg * 8 + i] * (float)kv[i];
    }
    ssm[j] = s;
    lmax = fmaxf(lmax, s);
  }
  red[tid] = lmax;
  __syncthreads();
  for (int sft = 128; sft > 0; sft >>= 1) {
    if (tid < sft) red[tid] = fmaxf(red[tid], red[tid + sft]);
    __syncthreads();
  }
  const float mx = red[0];
  __syncthreads();

  float lsum = 0.f;
  for (int j = tid; j < 1568; j += 256) {
    const float p = __expf(ssm[j] - mx);
    ssm[j] = p;
    lsum += p;
  }
  red[tid] = lsum;
  __syncthreads();
  for (int sft = 128; sft > 0; sft >>= 1) {
    if (tid < sft) red[tid] += red[tid + sft];
    __syncthreads();
  }
  const float inv = 1.f / red[0];
  __syncthreads();

  const int d = tid & 63, c = tid >> 6;
  float acc = 0.f;
  for (int fr = c * 2; fr < c * 2 + 2; ++fr) {
    const bf16* vp = Vt + ((long long)(bh * 8 + fr) * 64 + d) * 224;
    const float* pp = &ssm[fr * 196];
    for (int k = 0; k < 196; ++k) acc += pp[k] * (float)vp[k];
  }
  osm[c][d] = acc;
  __syncthreads();
  if (tid < 64) {
    const float o = (osm[0][tid] + osm[1][tid] + osm[2][tid] + osm[3][tid]) * inv;
    Ob[(long long)b * 1569 * 768 + h * 64 + tid] = (bf16)o;
  }
}

// ---------------------------------------------------------------------------
extern "C" void kernel_launch(void* const* d_in, const int* in_sizes, int n_in,
                              void* d_out, int out_size, void* d_ws, size_t ws_size,
                              hipStream_t stream) {
  const float* x        = (const float*)d_in[0];
  const float* question = (const float*)d_in[1];
  const float* Wq       = (const float*)d_in[2];
  const float* Wkv      = (const float*)d_in[3];
  const float* Wproj    = (const float*)d_in[4];
  const float* bproj    = (const float*)d_in[5];
  float* out = (float*)d_out;

  char* wsb = (char*)d_ws;
  const long long SZ_WQT  = 768LL * 768 * 2;
  const long long SZ_WKVT = 1536LL * 768 * 2;
  const long long SZ_WPT  = 768LL * 768 * 2;
  const long long SZ_QNB  = 32LL * 197 * 768 * 2;   // question bf16
  const long long SZ_Q    = 32LL * 197 * 768 * 2;   // q (scaled) bf16
  const long long SZ_K    = 384LL * 1568 * 64 * 2;
  const long long SZ_VO   = 50208LL * 768 * 2;      // max(Vb, Ob): Ob aliases Vb

  long long off = 0;
  bf16* Wqt  = (bf16*)(wsb + off); off += SZ_WQT;
  bf16* Wkvt = (bf16*)(wsb + off); off += SZ_WKVT;
  bf16* Wpt  = (bf16*)(wsb + off); off += SZ_WPT;
  bf16* qnb  = (bf16*)(wsb + off); off += SZ_QNB;
  bf16* qsb  = (bf16*)(wsb + off); off += SZ_Q;
  bf16* Kb   = (bf16*)(wsb + off); off += SZ_K;
  bf16* Vb   = (bf16*)(wsb + off); off += SZ_VO;
  bf16* Ob   = Vb;                     // alias: Vb dead after transv_k
  // xb (bf16 x, 77 MB) and Vt (88 MB) share one region: xb dead before transv.
  bf16* xb   = (bf16*)(wsb + off);
  bf16* Vt   = (bf16*)(wsb + off);

  const long long nx = 32LL * 1568 * 768;
  const long long nq = 32LL * 197 * 768;
  f2b_k<<<(int)((nx / 8 + 255) / 256), 256, 0, stream>>>(x, xb, nx);
  f2b_k<<<(int)((nq / 8 + 255) / 256), 256, 0, stream>>>(question, qnb, nq);

  wconv_k<<<(768 * 768) / 256, 256, 0, stream>>>(Wq, Wqt, 768, 768);
  wconv_k<<<(768 * 1536) / 256, 256, 0, stream>>>(Wkv, Wkvt, 768, 1536);
  wconv_k<<<(768 * 768) / 256, 256, 0, stream>>>(Wproj, Wpt, 768, 768);

  // q = (question @ Wq) * 0.125, bf16
  gemm_k<0><<<dim3(50, 6), 256, 0, stream>>>(qnb, Wqt, qsb, nullptr, nullptr,
                                             6304, 768, 768);
  // kv = x @ Wkv -> Kb, Vb (heads layout)
  gemm_k<1><<<dim3(392, 12), 256, 0, stream>>>(xb, Wkvt, Kb, Vb, nullptr,
                                               50176, 1536, 768);
  // V -> padded transposed layout (xb dead now; Vt overlays it)
  transv_k<<<(384 * 8 * 64 * 224) / 256, 256, 0, stream>>>(Vb, Vt);

  cls_k<<<384, 256, 0, stream>>>(qsb, Kb, Vt, Ob);
  attn_k<<<dim3(384, 8), 256, 0, stream>>>(qsb, Kb, Vt, Ob);

  // out = O @ Wproj + bproj (f32)
  gemm_k<2><<<dim3(393, 6), 256, 0, stream>>>(Ob, Wpt, out, nullptr, bproj,
                                              50208, 768, 768);
}